// Round 6
// baseline (238.408 us; speedup 1.0000x reference)
//
#include <hip/hip_runtime.h>
#include <math.h>

#define B_ 4
#define C_ 128
#define C8_ 16
#define H_ 128
#define W_ 128
#define HW_ 16384

// K0: WvT[k][c] = Wv[c][k]  (64 KB one-time transpose)
__global__ void wv_trans(const float* __restrict__ Wv, float* __restrict__ WvT) {
  int i = blockIdx.x * 256 + threadIdx.x;   // 16384 total
  int k = i >> 7, c = i & 127;
  WvT[i] = Wv[c * 128 + k];
}

// K1: q,k projections. Block = 64 pixels x 4 waves; wave g owns an 8-channel
// group (g<2: q[8g..8g+7], g>=2: k[...]). Weights staged transposed in LDS.
__global__ void qk_proj(const float* __restrict__ x,
                        const float* __restrict__ Wq, const float* __restrict__ bq,
                        const float* __restrict__ Wk, const float* __restrict__ bk,
                        float* __restrict__ qo, float* __restrict__ ko) {
  __shared__ float WT[128][36];   // [c][o], pad 36 keeps rows 16B-aligned
  int t = threadIdx.x;
  for (int i = t; i < 4096; i += 256) {
    int o = i >> 7, c = i & 127;              // coalesced global read of W rows
    WT[c][o] = (o < 16) ? Wq[o * 128 + c] : Wk[(o - 16) * 128 + c];
  }
  __syncthreads();
  int g = t >> 6, lane = t & 63;
  int P = blockIdx.x * 64 + lane;            // global pixel (b,hw)
  int b = P >> 14, hw = P & 16383;
  const float* xb = x + (size_t)b * C_ * HW_ + hw;
  const float* bsrc = (g < 2) ? (bq + g * 8) : (bk + (g - 2) * 8);
  float acc[8];
#pragma unroll
  for (int oi = 0; oi < 8; ++oi) acc[oi] = bsrc[oi];
#pragma unroll 4
  for (int c = 0; c < 128; ++c) {
    float xv = xb[(size_t)c * HW_];
    float4 w0 = *(const float4*)&WT[c][g * 8];
    float4 w1 = *(const float4*)&WT[c][g * 8 + 4];
    acc[0] = fmaf(w0.x, xv, acc[0]);
    acc[1] = fmaf(w0.y, xv, acc[1]);
    acc[2] = fmaf(w0.z, xv, acc[2]);
    acc[3] = fmaf(w0.w, xv, acc[3]);
    acc[4] = fmaf(w1.x, xv, acc[4]);
    acc[5] = fmaf(w1.y, xv, acc[5]);
    acc[6] = fmaf(w1.z, xv, acc[6]);
    acc[7] = fmaf(w1.w, xv, acc[7]);
  }
  float* dst = (g < 2) ? (qo + (size_t)P * 16 + g * 8)
                       : (ko + (size_t)P * 16 + (g - 2) * 8);
  float4 o0 = {acc[0], acc[1], acc[2], acc[3]};
  float4 o1 = {acc[4], acc[5], acc[6], acc[7]};
  *(float4*)dst       = o0;
  *(float4*)(dst + 4) = o1;
}

// K1b: qT/kT[b][w][h][16] = q/k_hwc[b][h][w][16].
__global__ void qkt_trans(const float* __restrict__ qo, const float* __restrict__ ko,
                          float* __restrict__ qT, float* __restrict__ kT) {
  int p = blockIdx.x * 256 + threadIdx.x;   // B*HW
  int b = p >> 14;
  int hw = p & 16383;
  int h = hw >> 7, w = hw & 127;
  size_t src = (size_t)p * 16;
  size_t dst = ((size_t)b * HW_ + (size_t)w * 128 + h) * 16;
#pragma unroll
  for (int r = 0; r < 4; ++r) ((float4*)(qT + dst))[r] = ((const float4*)(qo + src))[r];
#pragma unroll
  for (int r = 0; r < 4; ++r) ((float4*)(kT + dst))[r] = ((const float4*)(ko + src))[r];
}

// K2: score GEMM. S[slab][r][y] = sum_c Q[slab][r][c] * K[slab][y][c].
// Q,K: [slab][128][16]; S: [slab][128][128]. Grid = 512 slabs, 256 threads.
// Used twice: (q_hwc,k_hwc)->S_w[b][i][j][y] and (qT,kT)->S_h[b][j][i][y].
__global__ void score_gemm(const float* __restrict__ Q, const float* __restrict__ K,
                           float* __restrict__ S) {
  __shared__ float Qs[16][132];
  __shared__ float Ks[16][132];
  int slab = blockIdx.x;
  const float* qb = Q + (size_t)slab * 2048;
  const float* kb = K + (size_t)slab * 2048;
  int t = threadIdx.x;
  int cc = t & 15;           // c
  int pb = (t >> 4) * 8;     // p base
#pragma unroll
  for (int u = 0; u < 8; ++u) {
    Qs[cc][pb + u] = qb[(pb + u) * 16 + cc];
    Ks[cc][pb + u] = kb[(pb + u) * 16 + cc];
  }
  __syncthreads();
  int tr = (t >> 4) * 8;    // row tile
  int ty = (t & 15) * 8;    // col tile
  float acc[8][8] = {{0.f}};
#pragma unroll
  for (int c = 0; c < 16; ++c) {
    float qa[8], ka[8];
    *(float4*)(qa)     = *(const float4*)&Qs[c][tr];
    *(float4*)(qa + 4) = *(const float4*)&Qs[c][tr + 4];
    *(float4*)(ka)     = *(const float4*)&Ks[c][ty];
    *(float4*)(ka + 4) = *(const float4*)&Ks[c][ty + 4];
#pragma unroll
    for (int u = 0; u < 8; ++u)
#pragma unroll
      for (int v = 0; v < 8; ++v)
        acc[u][v] = fmaf(qa[u], ka[v], acc[u][v]);
  }
  float* out = S + (size_t)slab * 16384;
#pragma unroll
  for (int u = 0; u < 8; ++u) {
    float4 o0 = {acc[u][0], acc[u][1], acc[u][2], acc[u][3]};
    float4 o1 = {acc[u][4], acc[u][5], acc[u][6], acc[u][7]};
    *(float4*)&out[(tr + u) * 128 + ty]     = o0;
    *(float4*)&out[(tr + u) * 128 + ty + 4] = o1;
  }
}

// K3: streaming softmax. Block = (b, i, j-half). Reads S_h[b][j][i][:] and
// S_w[b][i][j][:] (contiguous per pixel), exp/sum/normalize, writes both
// transposed attn outputs in 256B row chunks. No max-sub (validated R3/R4).
__global__ void softmax_k(const float* __restrict__ Sh, const float* __restrict__ Sw,
                          float* __restrict__ ret) {
  __shared__ float sc[64][257];
  int blk = blockIdx.x;                 // B*128*2 = 1024
  int jh = blk & 1;
  int i = (blk >> 1) & 127;
  int b = blk >> 8;
  int wv = threadIdx.x >> 6, lane = threadIdx.x & 63;   // 8 waves
#pragma unroll 2
  for (int p = 0; p < 8; ++p) {
    int jl = wv * 8 + p;                // 0..63
    int j = jh * 64 + jl;
    const float* sh = Sh + (((size_t)(b * 128 + j) * 128) + i) * 128;
    const float* sw = Sw + (((size_t)(b * 128 + i) * 128) + j) * 128;
    float eh0 = sh[lane], eh1 = sh[lane + 64];
    float ew0 = sw[lane], ew1 = sw[lane + 64];
    eh0 = (lane == i) ? 0.f : __expf(eh0);
    eh1 = (lane + 64 == i) ? 0.f : __expf(eh1);
    ew0 = __expf(ew0);
    ew1 = __expf(ew1);
    float s = eh0 + eh1 + ew0 + ew1;
#pragma unroll
    for (int d = 32; d; d >>= 1) s += __shfl_xor(s, d);
    float inv = 1.0f / s;
    sc[jl][lane]       = eh0 * inv;
    sc[jl][lane + 64]  = eh1 * inv;
    sc[jl][lane + 128] = ew0 * inv;
    sc[jl][lane + 192] = ew1 * inv;
  }
  __syncthreads();
  int jl = threadIdx.x & 63;
  int y0 = threadIdx.x >> 6;   // 0..7
  for (int y = y0; y < 128; y += 8) {
    ret[(((size_t)(b * 2 + 0) * 128 + y) * 128 + i) * 128 + jh * 64 + jl] = sc[jl][y];
    ret[(((size_t)(b * 2 + 1) * 128 + y) * 128 + i) * 128 + jh * 64 + jl] = sc[jl][128 + y];
  }
}

// K4: v projection as LDS-tiled GEMM: v_hwc[p][c] = bv[c] + sum_k WvT[k][c]*x[b][k][p].
__global__ void v_proj_gemm(const float* __restrict__ x, const float* __restrict__ WvT,
                            const float* __restrict__ bv, float* __restrict__ vo) {
  __shared__ float Wc[32][132];
  __shared__ float Xc[32][132];
  int blk = blockIdx.x;          // B * HW/128 = 512
  int b = blk >> 7;
  int p0 = (blk & 127) * 128;
  int t = threadIdx.x;
  int tc = t & 15, tx = t >> 4;
  float acc[8][8];
#pragma unroll
  for (int ci = 0; ci < 8; ++ci) {
    float bvv = bv[tc * 8 + ci];
#pragma unroll
    for (int pi = 0; pi < 8; ++pi) acc[ci][pi] = bvv;
  }
  for (int k0 = 0; k0 < 128; k0 += 32) {
#pragma unroll
    for (int r = 0; r < 4; ++r) {
      int idx = r * 1024 + t * 4;
      int kl = idx >> 7, ccc = idx & 127;
      *(float4*)&Wc[kl][ccc] = *(const float4*)&WvT[(size_t)(k0 + kl) * 128 + ccc];
      *(float4*)&Xc[kl][ccc] =
          *(const float4*)&x[(size_t)b * C_ * HW_ + (size_t)(k0 + kl) * HW_ + p0 + ccc];
    }
    __syncthreads();
    for (int kl = 0; kl < 32; ++kl) {
      float wa[8], xa[8];
      *(float4*)(wa)     = *(const float4*)&Wc[kl][tc * 8];
      *(float4*)(wa + 4) = *(const float4*)&Wc[kl][tc * 8 + 4];
      *(float4*)(xa)     = *(const float4*)&Xc[kl][tx * 8];
      *(float4*)(xa + 4) = *(const float4*)&Xc[kl][tx * 8 + 4];
#pragma unroll
      for (int ci = 0; ci < 8; ++ci)
#pragma unroll
        for (int pi = 0; pi < 8; ++pi)
          acc[ci][pi] = fmaf(wa[ci], xa[pi], acc[ci][pi]);
    }
    __syncthreads();
  }
#pragma unroll
  for (int pi = 0; pi < 8; ++pi) {
    size_t base = ((size_t)(b * HW_ + p0 + tx * 8 + pi)) * 128 + tc * 8;
    float4 o0 = {acc[0][pi], acc[1][pi], acc[2][pi], acc[3][pi]};
    float4 o1 = {acc[4][pi], acc[5][pi], acc[6][pi], acc[7][pi]};
    *(float4*)&vo[base]     = o0;
    *(float4*)&vo[base + 4] = o1;
  }
}

// K5: ah[b][w][y][x] = ret0[b][y][x][w]  (tiled 64x64 transpose per (b,y))
__global__ void trans_ah(const float* __restrict__ ret, float* __restrict__ ah) {
  __shared__ float tile[64][65];
  int blk = blockIdx.x;               // b(4) * y(128) * quad(4)
  int q = blk & 3;
  int y = (blk >> 2) & 127;
  int b = blk >> 9;
  int x0 = (q >> 1) * 64, w0 = (q & 1) * 64;
  int t = threadIdx.x;
  int lane = t & 63;
  int r0 = (t >> 6) * 16;
  const float* src = ret + (((size_t)(b * 2) * 128 + y) * 128) * 128;
  for (int r = r0; r < r0 + 16; ++r)
    tile[r][lane] = src[(size_t)(x0 + r) * 128 + w0 + lane];
  __syncthreads();
  for (int r = r0; r < r0 + 16; ++r)
    ah[(((size_t)(b * 128 + w0 + r)) * 128 + y) * 128 + x0 + lane] = tile[lane][r];
}

// K6/K7: per-(b,slice) GEMM O[c][x] = sum_y V[y][c] * A[y][x]
template <int MODE>
__global__ void pv_gemm(const float* __restrict__ v_hwc, const float* __restrict__ ret,
                        const float* __restrict__ ah, const float* __restrict__ xin,
                        const float* __restrict__ gamma, float* __restrict__ outp,
                        float* __restrict__ oh) {
  __shared__ float Vc[32][132];
  __shared__ float Ac[32][132];
  int blk = blockIdx.x;       // B*128
  int s = blk & 127, b = blk >> 7;
  int t = threadIdx.x;
  int tc = t & 15, tx = t >> 4;
  float acc[8][8] = {{0.f}};
  for (int y0 = 0; y0 < 128; y0 += 32) {
#pragma unroll
    for (int r = 0; r < 4; ++r) {
      int idx = r * 1024 + t * 4;
      int yl = idx >> 7, cc = idx & 127;
      size_t vaddr, aaddr;
      if (MODE == 0) {
        vaddr = (((size_t)(b * 128 + s)) * 128 + (y0 + yl)) * 128 + cc;
        aaddr = (((size_t)(b * 2 + 1) * 128 + (y0 + yl)) * 128 + s) * 128 + cc;
      } else {
        vaddr = (((size_t)(b * 128 + (y0 + yl))) * 128 + s) * 128 + cc;
        aaddr = (((size_t)(b * 128 + s)) * 128 + (y0 + yl)) * 128 + cc;
      }
      *(float4*)&Vc[yl][cc] = *(const float4*)&v_hwc[vaddr];
      const float* asrc = (MODE == 0) ? ret : ah;
      *(float4*)&Ac[yl][cc] = *(const float4*)&asrc[aaddr];
    }
    __syncthreads();
    for (int yl = 0; yl < 32; ++yl) {
      float va[8], aa[8];
      *(float4*)(va)     = *(const float4*)&Vc[yl][tc * 8];
      *(float4*)(va + 4) = *(const float4*)&Vc[yl][tc * 8 + 4];
      *(float4*)(aa)     = *(const float4*)&Ac[yl][tx * 8];
      *(float4*)(aa + 4) = *(const float4*)&Ac[yl][tx * 8 + 4];
#pragma unroll
      for (int ci = 0; ci < 8; ++ci)
#pragma unroll
        for (int xi = 0; xi < 8; ++xi)
          acc[ci][xi] = fmaf(va[ci], aa[xi], acc[ci][xi]);
    }
    __syncthreads();
  }
  float g = gamma[0];
#pragma unroll
  for (int ci = 0; ci < 8; ++ci) {
    int c = tc * 8 + ci;
    if (MODE == 0) {
      size_t base = (((size_t)(b * 128 + c)) * 128 + s) * 128 + tx * 8;
#pragma unroll
      for (int xi = 0; xi < 8; ++xi)
        outp[base + xi] = g * acc[ci][xi] + xin[base + xi];
    } else {
      size_t base = (((size_t)(b * 128 + s)) * 128 + c) * 128 + tx * 8;
#pragma unroll
      for (int xi = 0; xi < 8; ++xi)
        oh[base + xi] = acc[ci][xi];
    }
  }
}

// K8: out[b][c][x][w] += gamma * oh[b][w][c][x]  (tiled transpose-add per (b,c))
__global__ void merge_k(const float* __restrict__ oh, const float* __restrict__ gamma,
                        float* __restrict__ outp) {
  __shared__ float tile[64][65];
  int blk = blockIdx.x;            // b(4) * c(128) * quad(4)
  int q = blk & 3;
  int c = (blk >> 2) & 127;
  int b = blk >> 9;
  int x0 = (q >> 1) * 64, w0 = (q & 1) * 64;
  int t = threadIdx.x;
  int lane = t & 63;
  int r0 = (t >> 6) * 16;
  for (int r = r0; r < r0 + 16; ++r)
    tile[r][lane] = oh[(((size_t)(b * 128 + w0 + r)) * 128 + c) * 128 + x0 + lane];
  __syncthreads();
  float g = gamma[0];
  for (int r = r0; r < r0 + 16; ++r) {
    size_t a = (((size_t)(b * 128 + c)) * 128 + x0 + r) * 128 + w0 + lane;
    outp[a] += g * tile[lane][r];
  }
}

extern "C" void kernel_launch(void* const* d_in, const int* in_sizes, int n_in,
                              void* d_out, int out_size, void* d_ws, size_t ws_size,
                              hipStream_t stream) {
  const float* x     = (const float*)d_in[0];
  const float* Wq    = (const float*)d_in[1];
  const float* bq    = (const float*)d_in[2];
  const float* Wk    = (const float*)d_in[3];
  const float* bk    = (const float*)d_in[4];
  const float* Wv    = (const float*)d_in[5];
  const float* bv    = (const float*)d_in[6];
  const float* gamma = (const float*)d_in[7];

  float* outp = (float*)d_out;                 // 8388608 (final out; S_w scratch early)
  float* ret  = outp + (size_t)8388608;        // 16777216 (attn outputs)

  // Workspace lifetime plan (floats):
  //  [0,1048576)        q_hwc   (dead after score_w)
  //  [1048576,2097152)  k_hwc   (dead after score_w)
  //  [2097152,3145728)  qT      (dead after score_h)
  //  [3145728,4194304)  kT      (dead after score_h)
  //  [0,8388608)        v_hwc   (written by v_proj AFTER the above are dead)
  //  [8388608,8404992)  WvT     (written first, read by v_proj; outside v_hwc)
  //  [10485760,18874368) S_h    (dead after softmax) -> then ah/oh
  //  S_w lives in outp[0,8388608) (dead after softmax; pv0 rewrites fully)
  float* ws    = (float*)d_ws;
  float* q_hwc = ws;
  float* k_hwc = ws + (size_t)1048576;
  float* qT    = ws + (size_t)2097152;
  float* kT    = ws + (size_t)3145728;
  float* v_hwc = ws;
  float* WvT   = ws + (size_t)8388608;
  float* S_h   = ws + (size_t)10485760;
  float* ah    = ws + (size_t)10485760;
  float* S_w   = outp;

  wv_trans<<<64, 256, 0, stream>>>(Wv, WvT);
  qk_proj<<<1024, 256, 0, stream>>>(x, Wq, bq, Wk, bk, q_hwc, k_hwc);
  qkt_trans<<<256, 256, 0, stream>>>(q_hwc, k_hwc, qT, kT);
  score_gemm<<<512, 256, 0, stream>>>(q_hwc, k_hwc, S_w);   // S_w[b][i][j][y]
  score_gemm<<<512, 256, 0, stream>>>(qT, kT, S_h);         // S_h[b][j][i][y]
  softmax_k<<<1024, 512, 0, stream>>>(S_h, S_w, ret);
  v_proj_gemm<<<512, 256, 0, stream>>>(x, WvT, bv, v_hwc);
  trans_ah<<<2048, 256, 0, stream>>>(ret, ah);
  pv_gemm<0><<<512, 256, 0, stream>>>(v_hwc, ret, ah, x, gamma, outp, ah);
  pv_gemm<1><<<512, 256, 0, stream>>>(v_hwc, ret, ah, x, gamma, outp, ah);
  merge_k<<<2048, 256, 0, stream>>>(ah, gamma, outp);
}

// Round 8
// 216.175 us; speedup vs baseline: 1.1028x; 1.1028x over previous
//
#include <hip/hip_runtime.h>
#include <math.h>

#define B_ 4
#define C_ 128
#define HW_ 16384
#define SLOT_ 2097152ULL     // 128^3 floats (one attn plane)
#define BSTR_ 4194304ULL     // per-batch stride in attn region (2 slots)

// K1: q,k projections. Block = 64 pixels x 4 waves; wave g owns an 8-channel
// group (g<2: q, g>=2: k). Writes pixel-major q/k AND (b,w,h)-transposed qT/kT.
__global__ void qk_proj(const float* __restrict__ x,
                        const float* __restrict__ Wq, const float* __restrict__ bq,
                        const float* __restrict__ Wk, const float* __restrict__ bk,
                        float* __restrict__ qo, float* __restrict__ ko,
                        float* __restrict__ qT, float* __restrict__ kT) {
  __shared__ float WT[128][36];
  int t = threadIdx.x;
  for (int i = t; i < 4096; i += 256) {
    int o = i >> 7, c = i & 127;
    WT[c][o] = (o < 16) ? Wq[o * 128 + c] : Wk[(o - 16) * 128 + c];
  }
  __syncthreads();
  int g = t >> 6, lane = t & 63;
  int P = blockIdx.x * 64 + lane;
  int b = P >> 14, hw = P & 16383;
  int h = hw >> 7, w = hw & 127;
  const float* xb = x + (size_t)b * C_ * HW_ + hw;
  const float* bsrc = (g < 2) ? (bq + g * 8) : (bk + (g - 2) * 8);
  float acc[8];
#pragma unroll
  for (int oi = 0; oi < 8; ++oi) acc[oi] = bsrc[oi];
#pragma unroll 4
  for (int c = 0; c < 128; ++c) {
    float xv = xb[(size_t)c * HW_];
    float4 w0 = *(const float4*)&WT[c][g * 8];
    float4 w1 = *(const float4*)&WT[c][g * 8 + 4];
    acc[0] = fmaf(w0.x, xv, acc[0]);
    acc[1] = fmaf(w0.y, xv, acc[1]);
    acc[2] = fmaf(w0.z, xv, acc[2]);
    acc[3] = fmaf(w0.w, xv, acc[3]);
    acc[4] = fmaf(w1.x, xv, acc[4]);
    acc[5] = fmaf(w1.y, xv, acc[5]);
    acc[6] = fmaf(w1.z, xv, acc[6]);
    acc[7] = fmaf(w1.w, xv, acc[7]);
  }
  float4 o0 = {acc[0], acc[1], acc[2], acc[3]};
  float4 o1 = {acc[4], acc[5], acc[6], acc[7]};
  int go = (g & 1) * 8;
  float* dst = ((g < 2) ? qo : ko) + (size_t)P * 16 + go;
  *(float4*)dst       = o0;
  *(float4*)(dst + 4) = o1;
  float* dstT = ((g < 2) ? qT : kT) + ((size_t)b * HW_ + (size_t)w * 128 + h) * 16 + go;
  *(float4*)dstT       = o0;
  *(float4*)(dstT + 4) = o1;
}

// K2: score GEMM + exp + row-sums. Slab (b,s): E[r][y] = exp(Q[r]·K[y])
// (MASK zeroes r==y). Slab plane stored at E + b*bs + off + s*16384.
template <int MASK>
__global__ void score_gemm(const float* __restrict__ Q, const float* __restrict__ K,
                           float* __restrict__ E, float* __restrict__ rsum,
                           size_t bs, size_t off) {
  __shared__ float Qs[16][132];
  __shared__ float Ks[16][132];
  int slab = blockIdx.x;
  const float* qb = Q + (size_t)slab * 2048;
  const float* kb = K + (size_t)slab * 2048;
  int t = threadIdx.x;
  int cc = t & 15;
  int pb = (t >> 4) * 8;
#pragma unroll
  for (int u = 0; u < 8; ++u) {
    Qs[cc][pb + u] = qb[(pb + u) * 16 + cc];
    Ks[cc][pb + u] = kb[(pb + u) * 16 + cc];
  }
  __syncthreads();
  int tr = (t >> 4) * 8;
  int ty = (t & 15) * 8;
  float acc[8][8] = {{0.f}};
#pragma unroll
  for (int c = 0; c < 16; ++c) {
    float qa[8], ka[8];
    *(float4*)(qa)     = *(const float4*)&Qs[c][tr];
    *(float4*)(qa + 4) = *(const float4*)&Qs[c][tr + 4];
    *(float4*)(ka)     = *(const float4*)&Ks[c][ty];
    *(float4*)(ka + 4) = *(const float4*)&Ks[c][ty + 4];
#pragma unroll
    for (int u = 0; u < 8; ++u)
#pragma unroll
      for (int v = 0; v < 8; ++v)
        acc[u][v] = fmaf(qa[u], ka[v], acc[u][v]);
  }
  float rp[8];
#pragma unroll
  for (int u = 0; u < 8; ++u) {
    rp[u] = 0.f;
#pragma unroll
    for (int v = 0; v < 8; ++v) {
      float e = __expf(acc[u][v]);
      if (MASK && (tr + u) == (ty + v)) e = 0.f;
      acc[u][v] = e;
      rp[u] += e;
    }
  }
  float* out = E + (size_t)(slab >> 7) * bs + off + (size_t)(slab & 127) * 16384;
#pragma unroll
  for (int u = 0; u < 8; ++u) {
    float4 e0 = {acc[u][0], acc[u][1], acc[u][2], acc[u][3]};
    float4 e1 = {acc[u][4], acc[u][5], acc[u][6], acc[u][7]};
    *(float4*)&out[(tr + u) * 128 + ty]     = e0;
    *(float4*)&out[(tr + u) * 128 + ty + 4] = e1;
  }
#pragma unroll
  for (int u = 0; u < 8; ++u) {
    rp[u] += __shfl_xor(rp[u], 1);
    rp[u] += __shfl_xor(rp[u], 2);
    rp[u] += __shfl_xor(rp[u], 4);
    rp[u] += __shfl_xor(rp[u], 8);
  }
  if ((t & 15) == 0) {
#pragma unroll
    for (int u = 0; u < 8; ++u) rsum[(size_t)slab * 128 + tr + u] = rp[u];
  }
}

// K3: per-pixel inverse denominator, (i,j) and (j,i) layouts.
__global__ void invd_k(const float* __restrict__ rsw, const float* __restrict__ rsh,
                       float* __restrict__ dij, float* __restrict__ dji) {
  int p = blockIdx.x * 256 + threadIdx.x;
  int b = p >> 14, rem = p & 16383, i = rem >> 7, j = rem & 127;
  float d = rsw[p] + rsh[(size_t)b * HW_ + j * 128 + i];
  float r = 1.0f / d;
  dij[p] = r;
  dji[(size_t)b * HW_ + j * 128 + i] = r;
}

// K4: v projection GEMM (Wv staged transposed from global).
__global__ void v_proj_gemm(const float* __restrict__ x, const float* __restrict__ Wv,
                            const float* __restrict__ bv, float* __restrict__ vo) {
  __shared__ float Wc[32][132];
  __shared__ float Xc[32][132];
  int blk = blockIdx.x;
  int b = blk >> 7;
  int p0 = (blk & 127) * 128;
  int t = threadIdx.x;
  int tc = t & 15, tx = t >> 4;
  float acc[8][8];
#pragma unroll
  for (int ci = 0; ci < 8; ++ci) {
    float bvv = bv[tc * 8 + ci];
#pragma unroll
    for (int pi = 0; pi < 8; ++pi) acc[ci][pi] = bvv;
  }
  int c2 = t >> 1, part = t & 1;
  for (int k0 = 0; k0 < 128; k0 += 32) {
#pragma unroll
    for (int qq = 0; qq < 4; ++qq) {
      int y4 = part * 16 + qq * 4;
      float4 w4 = *(const float4*)&Wv[c2 * 128 + k0 + y4];
      Wc[y4 + 0][c2] = w4.x;
      Wc[y4 + 1][c2] = w4.y;
      Wc[y4 + 2][c2] = w4.z;
      Wc[y4 + 3][c2] = w4.w;
    }
#pragma unroll
    for (int r = 0; r < 4; ++r) {
      int idx = r * 1024 + t * 4;
      int kl = idx >> 7, ccc = idx & 127;
      *(float4*)&Xc[kl][ccc] =
          *(const float4*)&x[(size_t)b * C_ * HW_ + (size_t)(k0 + kl) * HW_ + p0 + ccc];
    }
    __syncthreads();
    for (int kl = 0; kl < 32; ++kl) {
      float wa[8], xa[8];
      *(float4*)(wa)     = *(const float4*)&Wc[kl][tc * 8];
      *(float4*)(wa + 4) = *(const float4*)&Wc[kl][tc * 8 + 4];
      *(float4*)(xa)     = *(const float4*)&Xc[kl][tx * 8];
      *(float4*)(xa + 4) = *(const float4*)&Xc[kl][tx * 8 + 4];
#pragma unroll
      for (int ci = 0; ci < 8; ++ci)
#pragma unroll
        for (int pi = 0; pi < 8; ++pi)
          acc[ci][pi] = fmaf(wa[ci], xa[pi], acc[ci][pi]);
    }
    __syncthreads();
  }
#pragma unroll
  for (int pi = 0; pi < 8; ++pi) {
    size_t base = ((size_t)(b * HW_ + p0 + tx * 8 + pi)) * 128 + tc * 8;
    float4 o0 = {acc[0][pi], acc[1][pi], acc[2][pi], acc[3][pi]};
    float4 o1 = {acc[4][pi], acc[5][pi], acc[6][pi], acc[7][pi]};
    *(float4*)&vo[base]     = o0;
    *(float4*)&vo[base + 4] = o1;
  }
}

// K5/K6: PV GEMM. O[c][x] = sum_y V[y][c] * E[slab][x][y], scaled by invd[x].
// E slab plane at E + b*bsE + offE + s*16384.
// MODE 0 (out_w, slab=h): writes out = g*O*invd + xin   (outd = final out).
// MODE 1 (out_h, slab=w): writes oh[b-even-slot][w][c][x] = O*invd (outd = attn base).
template <int MODE>
__global__ void pv_gemm(const float* __restrict__ v_hwc, const float* __restrict__ E,
                        const float* __restrict__ invd, const float* __restrict__ xin,
                        const float* __restrict__ gamma, float* __restrict__ outd,
                        size_t bsE, size_t offE) {
  __shared__ float Vc[32][132];
  __shared__ float Ac[32][132];
  int blk = blockIdx.x;
  int s = blk & 127, b = blk >> 7;
  int t = threadIdx.x;
  int tc = t & 15, tx = t >> 4;
  const float* Eb = E + (size_t)b * bsE + offE + (size_t)s * 16384;
  int x2 = t >> 1, part = t & 1;
  float acc[8][8] = {{0.f}};
  for (int y0 = 0; y0 < 128; y0 += 32) {
#pragma unroll
    for (int r = 0; r < 4; ++r) {
      int idx = r * 1024 + t * 4;
      int yl = idx >> 7, cc = idx & 127;
      size_t vaddr = (MODE == 0)
          ? (((size_t)(b * 128 + s)) * 128 + (y0 + yl)) * 128 + cc
          : (((size_t)(b * 128 + (y0 + yl))) * 128 + s) * 128 + cc;
      *(float4*)&Vc[yl][cc] = *(const float4*)&v_hwc[vaddr];
    }
#pragma unroll
    for (int qq = 0; qq < 4; ++qq) {
      int y4 = part * 16 + qq * 4;
      float4 e4 = *(const float4*)&Eb[(size_t)x2 * 128 + y0 + y4];
      Ac[y4 + 0][x2] = e4.x;
      Ac[y4 + 1][x2] = e4.y;
      Ac[y4 + 2][x2] = e4.z;
      Ac[y4 + 3][x2] = e4.w;
    }
    __syncthreads();
    for (int yl = 0; yl < 32; ++yl) {
      float va[8], aa[8];
      *(float4*)(va)     = *(const float4*)&Vc[yl][tc * 8];
      *(float4*)(va + 4) = *(const float4*)&Vc[yl][tc * 8 + 4];
      *(float4*)(aa)     = *(const float4*)&Ac[yl][tx * 8];
      *(float4*)(aa + 4) = *(const float4*)&Ac[yl][tx * 8 + 4];
#pragma unroll
      for (int ci = 0; ci < 8; ++ci)
#pragma unroll
        for (int xi = 0; xi < 8; ++xi)
          acc[ci][xi] = fmaf(va[ci], aa[xi], acc[ci][xi]);
    }
    __syncthreads();
  }
  float g = gamma[0];
  float idv[8];
  *(float4*)(idv)     = *(const float4*)&invd[(size_t)(b * 128 + s) * 128 + tx * 8];
  *(float4*)(idv + 4) = *(const float4*)&invd[(size_t)(b * 128 + s) * 128 + tx * 8 + 4];
#pragma unroll
  for (int ci = 0; ci < 8; ++ci) {
    int c = tc * 8 + ci;
    if (MODE == 0) {
      size_t base = (((size_t)(b * 128 + c)) * 128 + s) * 128 + tx * 8;
#pragma unroll
      for (int xi = 0; xi < 8; ++xi)
        outd[base + xi] = g * acc[ci][xi] * idv[xi] + xin[base + xi];
    } else {
      size_t base = (size_t)b * BSTR_ + (size_t)s * 16384 + (size_t)c * 128 + tx * 8;
#pragma unroll
      for (int xi = 0; xi < 8; ++xi)
        outd[base + xi] = acc[ci][xi] * idv[xi];
    }
  }
}

// K7: out[b][c][x][w] += gamma * oh[b][w][c][x], oh in even attn slots.
__global__ void merge_k(const float* __restrict__ retb, const float* __restrict__ gamma,
                        float* __restrict__ outp) {
  __shared__ float tile[64][65];
  int blk = blockIdx.x;
  int q = blk & 3;
  int c = (blk >> 2) & 127;
  int b = blk >> 9;
  int x0 = (q >> 1) * 64, w0 = (q & 1) * 64;
  int t = threadIdx.x;
  int lane = t & 63;
  int r0 = (t >> 6) * 16;
  for (int r = r0; r < r0 + 16; ++r)
    tile[r][lane] = retb[(size_t)b * BSTR_ + (size_t)(w0 + r) * 16384 + c * 128 + x0 + lane];
  __syncthreads();
  float g = gamma[0];
  for (int r = r0; r < r0 + 16; ++r) {
    size_t a = (((size_t)(b * 128 + c)) * 128 + x0 + r) * 128 + w0 + lane;
    outp[a] += g * tile[lane][r];
  }
}

// K8: attn writer. Block = (b,i). Writes ret[b][HM?0:1-slot][y][i][j] =
// tile[j][y] * invd_ij[b][i][j], coalesced 512B rows.
// HM=0: src = E_w plane (b,i) in ws (rows j, cols y), dst = odd slot (attn_w).
// HM=1: src = E_h in odd slots, gather rows E_h[b][j][i][:], dst = even slot.
template <int HM>
__global__ void ret_write(const float* __restrict__ src, const float* __restrict__ invd,
                          float* __restrict__ retb) {
  __shared__ float tile[128][129];
  __shared__ float idv[128];
  int slab = blockIdx.x;            // b*128 + i
  int b = slab >> 7, i = slab & 127;
  int t = threadIdx.x;
#pragma unroll
  for (int r = 0; r < 16; ++r) {
    int idx = r * 1024 + t * 4;
    int j = idx >> 7, y = idx & 127;
    float4 vv;
    if (HM == 0)
      vv = *(const float4*)&src[(size_t)slab * 16384 + j * 128 + y];
    else
      vv = *(const float4*)&src[(size_t)b * BSTR_ + SLOT_ + (size_t)j * 16384 + i * 128 + y];
    tile[j][y]     = vv.x;
    tile[j][y + 1] = vv.y;
    tile[j][y + 2] = vv.z;
    tile[j][y + 3] = vv.w;
  }
  if (t < 128) idv[t] = invd[(size_t)slab * 128 + t];
  __syncthreads();
  float* dp = retb + (size_t)b * BSTR_ + (HM == 0 ? SLOT_ : 0);
#pragma unroll
  for (int r = 0; r < 16; ++r) {
    int idx = r * 1024 + t * 4;
    int y = idx >> 7, j = idx & 127;
    float4 o;
    o.x = tile[j][y]     * idv[j];
    o.y = tile[j + 1][y] * idv[j + 1];
    o.z = tile[j + 2][y] * idv[j + 2];
    o.w = tile[j + 3][y] * idv[j + 3];
    *(float4*)&dp[(size_t)y * 16384 + i * 128 + j] = o;
  }
}

extern "C" void kernel_launch(void* const* d_in, const int* in_sizes, int n_in,
                              void* d_out, int out_size, void* d_ws, size_t ws_size,
                              hipStream_t stream) {
  const float* x     = (const float*)d_in[0];
  const float* Wq    = (const float*)d_in[1];
  const float* bq    = (const float*)d_in[2];
  const float* Wk    = (const float*)d_in[3];
  const float* bk    = (const float*)d_in[4];
  const float* Wv    = (const float*)d_in[5];
  const float* bv    = (const float*)d_in[6];
  const float* gamma = (const float*)d_in[7];

  float* outp = (float*)d_out;                 // final out [b][c][h][w] (8M floats)
  float* retb = outp + (size_t)8388608;        // attn region [b][2][y][i][j] (16M)
  // even slots (b*BSTR_): oh scratch, then attn_h. odd slots (+SLOT_): E_h, then attn_w.

  float* ws      = (float*)d_ws;
  float* q_hwc   = ws;                          // dead after score<0>
  float* k_hwc   = ws + (size_t)1048576;
  float* qT      = ws + (size_t)2097152;        // dead after score<1>
  float* kT      = ws + (size_t)3145728;
  float* v_hwc   = ws;                          // written by v_proj (q/k dead)
  float* E_w     = ws + (size_t)8388608;        // 8M floats
  float* rsum_w  = ws + (size_t)16777216;
  float* rsum_h  = ws + (size_t)16842752;
  float* invd_ij = ws + (size_t)16908288;
  float* invd_ji = ws + (size_t)16973824;

  qk_proj<<<1024, 256, 0, stream>>>(x, Wq, bq, Wk, bk, q_hwc, k_hwc, qT, kT);
  score_gemm<0><<<512, 256, 0, stream>>>(q_hwc, k_hwc, E_w, rsum_w,
                                         (size_t)SLOT_, (size_t)0);       // E_w in ws
  score_gemm<1><<<512, 256, 0, stream>>>(qT, kT, retb, rsum_h,
                                         (size_t)BSTR_, (size_t)SLOT_);   // E_h odd slots
  invd_k<<<256, 256, 0, stream>>>(rsum_w, rsum_h, invd_ij, invd_ji);
  v_proj_gemm<<<512, 256, 0, stream>>>(x, Wv, bv, v_hwc);
  pv_gemm<0><<<512, 256, 0, stream>>>(v_hwc, E_w, invd_ij, x, gamma, outp,
                                      (size_t)SLOT_, (size_t)0);
  pv_gemm<1><<<512, 256, 0, stream>>>(v_hwc, retb, invd_ji, x, gamma, retb,
                                      (size_t)BSTR_, (size_t)SLOT_);      // oh -> even slots
  merge_k<<<2048, 256, 0, stream>>>(retb, gamma, outp);
  ret_write<1><<<512, 256, 0, stream>>>(retb, invd_ij, retb);  // E_h(odd) -> attn_h(even)
  ret_write<0><<<512, 256, 0, stream>>>(E_w, invd_ij, retb);   // E_w(ws)  -> attn_w(odd)
}

// Round 9
// 163.289 us; speedup vs baseline: 1.4600x; 1.3239x over previous
//
#include <hip/hip_runtime.h>
#include <math.h>

#define HW_ 16384
#define SLOT_ 2097152ULL     // 128^3 floats (one attn plane)
#define BSTR_ 4194304ULL     // per-batch float stride in attn region (2 slots)

typedef __attribute__((ext_vector_type(8))) short short8v;   // 8 bf16 = 4 VGPR
typedef __attribute__((ext_vector_type(4))) float f32x4;

__device__ __forceinline__ unsigned short f2bf(float f) {
  unsigned int u = __float_as_uint(f);
  u = (u + 0x7FFFu + ((u >> 16) & 1u)) >> 16;   // RNE
  return (unsigned short)u;
}
__device__ __forceinline__ float bf2f(unsigned short h) {
  return __uint_as_float(((unsigned int)h) << 16);
}

// K1: q,k projections (fp32). Writes pixel-major q/k and (b,w,h)-transposed qT/kT.
__global__ void qk_proj(const float* __restrict__ x,
                        const float* __restrict__ Wq, const float* __restrict__ bq,
                        const float* __restrict__ Wk, const float* __restrict__ bk,
                        float* __restrict__ qo, float* __restrict__ ko,
                        float* __restrict__ qT, float* __restrict__ kT) {
  __shared__ float WT[128][36];
  int t = threadIdx.x;
  for (int i = t; i < 4096; i += 256) {
    int o = i >> 7, c = i & 127;
    WT[c][o] = (o < 16) ? Wq[o * 128 + c] : Wk[(o - 16) * 128 + c];
  }
  __syncthreads();
  int g = t >> 6, lane = t & 63;
  int P = blockIdx.x * 64 + lane;
  int b = P >> 14, hw = P & 16383;
  int h = hw >> 7, w = hw & 127;
  const float* xb = x + (size_t)b * 128 * HW_ + hw;
  const float* bsrc = (g < 2) ? (bq + g * 8) : (bk + (g - 2) * 8);
  float acc[8];
#pragma unroll
  for (int oi = 0; oi < 8; ++oi) acc[oi] = bsrc[oi];
#pragma unroll 4
  for (int c = 0; c < 128; ++c) {
    float xv = xb[(size_t)c * HW_];
    float4 w0 = *(const float4*)&WT[c][g * 8];
    float4 w1 = *(const float4*)&WT[c][g * 8 + 4];
    acc[0] = fmaf(w0.x, xv, acc[0]);
    acc[1] = fmaf(w0.y, xv, acc[1]);
    acc[2] = fmaf(w0.z, xv, acc[2]);
    acc[3] = fmaf(w0.w, xv, acc[3]);
    acc[4] = fmaf(w1.x, xv, acc[4]);
    acc[5] = fmaf(w1.y, xv, acc[5]);
    acc[6] = fmaf(w1.z, xv, acc[6]);
    acc[7] = fmaf(w1.w, xv, acc[7]);
  }
  float4 o0 = {acc[0], acc[1], acc[2], acc[3]};
  float4 o1 = {acc[4], acc[5], acc[6], acc[7]};
  int go = (g & 1) * 8;
  float* dst = ((g < 2) ? qo : ko) + (size_t)P * 16 + go;
  *(float4*)dst       = o0;
  *(float4*)(dst + 4) = o1;
  float* dstT = ((g < 2) ? qT : kT) + ((size_t)b * HW_ + (size_t)w * 128 + h) * 16 + go;
  *(float4*)dstT       = o0;
  *(float4*)(dstT + 4) = o1;
}

// K2: score GEMM + exp + row-sums; E stored bf16. Plane at E + slab*16384.
template <int MASK>
__global__ void score_b(const float* __restrict__ Q, const float* __restrict__ K,
                        unsigned short* __restrict__ E, float* __restrict__ rsum) {
  __shared__ float Qs[16][132];
  __shared__ float Ks[16][132];
  int slab = blockIdx.x;
  const float* qb = Q + (size_t)slab * 2048;
  const float* kb = K + (size_t)slab * 2048;
  int t = threadIdx.x;
  int cc = t & 15;
  int pb = (t >> 4) * 8;
#pragma unroll
  for (int u = 0; u < 8; ++u) {
    Qs[cc][pb + u] = qb[(pb + u) * 16 + cc];
    Ks[cc][pb + u] = kb[(pb + u) * 16 + cc];
  }
  __syncthreads();
  int tr = (t >> 4) * 8;
  int ty = (t & 15) * 8;
  float acc[8][8] = {{0.f}};
#pragma unroll
  for (int c = 0; c < 16; ++c) {
    float qa[8], ka[8];
    *(float4*)(qa)     = *(const float4*)&Qs[c][tr];
    *(float4*)(qa + 4) = *(const float4*)&Qs[c][tr + 4];
    *(float4*)(ka)     = *(const float4*)&Ks[c][ty];
    *(float4*)(ka + 4) = *(const float4*)&Ks[c][ty + 4];
#pragma unroll
    for (int u = 0; u < 8; ++u)
#pragma unroll
      for (int v = 0; v < 8; ++v)
        acc[u][v] = fmaf(qa[u], ka[v], acc[u][v]);
  }
  float rp[8];
#pragma unroll
  for (int u = 0; u < 8; ++u) {
    rp[u] = 0.f;
#pragma unroll
    for (int v = 0; v < 8; ++v) {
      float e = __expf(acc[u][v]);
      if (MASK && (tr + u) == (ty + v)) e = 0.f;
      acc[u][v] = e;
      rp[u] += e;
    }
  }
  unsigned short* out = E + (size_t)slab * 16384;
#pragma unroll
  for (int u = 0; u < 8; ++u) {
    union { unsigned short us[8]; uint4 v; } pk;
#pragma unroll
    for (int v = 0; v < 8; ++v) pk.us[v] = f2bf(acc[u][v]);
    *(uint4*)&out[(tr + u) * 128 + ty] = pk.v;
  }
#pragma unroll
  for (int u = 0; u < 8; ++u) {
    rp[u] += __shfl_xor(rp[u], 1);
    rp[u] += __shfl_xor(rp[u], 2);
    rp[u] += __shfl_xor(rp[u], 4);
    rp[u] += __shfl_xor(rp[u], 8);
  }
  if ((t & 15) == 0) {
#pragma unroll
    for (int u = 0; u < 8; ++u) rsum[(size_t)slab * 128 + tr + u] = rp[u];
  }
}

// K3: per-pixel inverse denominator, (i,j) and (j,i) layouts.
__global__ void invd_k(const float* __restrict__ rsw, const float* __restrict__ rsh,
                       float* __restrict__ dij, float* __restrict__ dji) {
  int p = blockIdx.x * 256 + threadIdx.x;
  int b = p >> 14, rem = p & 16383, i = rem >> 7, j = rem & 127;
  float d = rsw[p] + rsh[(size_t)b * HW_ + j * 128 + i];
  float r = 1.0f / d;
  dij[p] = r;
  dji[(size_t)b * HW_ + j * 128 + i] = r;
}

// K4: v projection GEMM -> bf16 vA0[b][h][c][w] ([c][y]-major per row slab).
__global__ void v_proj_bf(const float* __restrict__ x, const float* __restrict__ Wv,
                          const float* __restrict__ bv, unsigned short* __restrict__ vA0) {
  __shared__ float Wc[32][132];
  __shared__ float Xc[32][132];
  int blk = blockIdx.x;          // b*128 + h
  int b = blk >> 7;
  int h = blk & 127;
  int p0 = h * 128;
  int t = threadIdx.x;
  int tc = t & 15, tx = t >> 4;
  float acc[8][8];
#pragma unroll
  for (int ci = 0; ci < 8; ++ci) {
    float bvv = bv[tc * 8 + ci];
#pragma unroll
    for (int pi = 0; pi < 8; ++pi) acc[ci][pi] = bvv;
  }
  int c2 = t >> 1, part = t & 1;
  for (int k0 = 0; k0 < 128; k0 += 32) {
#pragma unroll
    for (int qq = 0; qq < 4; ++qq) {
      int y4 = part * 16 + qq * 4;
      float4 w4 = *(const float4*)&Wv[c2 * 128 + k0 + y4];
      Wc[y4 + 0][c2] = w4.x;
      Wc[y4 + 1][c2] = w4.y;
      Wc[y4 + 2][c2] = w4.z;
      Wc[y4 + 3][c2] = w4.w;
    }
#pragma unroll
    for (int r = 0; r < 4; ++r) {
      int idx = r * 1024 + t * 4;
      int kl = idx >> 7, ccc = idx & 127;
      *(float4*)&Xc[kl][ccc] =
          *(const float4*)&x[(size_t)b * 128 * HW_ + (size_t)(k0 + kl) * HW_ + p0 + ccc];
    }
    __syncthreads();
    for (int kl = 0; kl < 32; ++kl) {
      float wa[8], xa[8];
      *(float4*)(wa)     = *(const float4*)&Wc[kl][tc * 8];
      *(float4*)(wa + 4) = *(const float4*)&Wc[kl][tc * 8 + 4];
      *(float4*)(xa)     = *(const float4*)&Xc[kl][tx * 8];
      *(float4*)(xa + 4) = *(const float4*)&Xc[kl][tx * 8 + 4];
#pragma unroll
      for (int ci = 0; ci < 8; ++ci)
#pragma unroll
        for (int pi = 0; pi < 8; ++pi)
          acc[ci][pi] = fmaf(wa[ci], xa[pi], acc[ci][pi]);
    }
    __syncthreads();
  }
#pragma unroll
  for (int ci = 0; ci < 8; ++ci) {
    union { unsigned short us[8]; uint4 v; } pk;
#pragma unroll
    for (int pi = 0; pi < 8; ++pi) pk.us[pi] = f2bf(acc[ci][pi]);
    *(uint4*)&vA0[(size_t)(b * 128 + h) * 16384 + (size_t)(tc * 8 + ci) * 128 + tx * 8] = pk.v;
  }
}

// K4b: vA1[b][w][c][h] = vA0[b][h][c][w]  (bf16 64x64 tiled transpose per (b,c))
__global__ void trans_v(const unsigned short* __restrict__ vA0, unsigned short* __restrict__ vA1) {
  __shared__ unsigned short tile[64][65];
  int blk = blockIdx.x;            // b(4)*c(128)*quad(4)
  int q = blk & 3, c = (blk >> 2) & 127, b = blk >> 9;
  int h0 = (q >> 1) * 64, w0 = (q & 1) * 64;
  int t = threadIdx.x, lane = t & 63, r0 = (t >> 6) * 16;
  for (int r = r0; r < r0 + 16; ++r)
    tile[r][lane] = vA0[(size_t)(b * 128 + h0 + r) * 16384 + c * 128 + w0 + lane];
  __syncthreads();
  for (int r = r0; r < r0 + 16; ++r)
    vA1[(size_t)(b * 128 + w0 + r) * 16384 + c * 128 + h0 + lane] = tile[lane][r];
}

// K5/K6: PV via MFMA. O[c][x] = sum_y A[c][y]*B[y][x], A = vA slab ([c][y] bf16
// row-major), B^T = E slab ([x][y] bf16 row-major). 4 waves, each 64x64 output.
// MODE 0: out = g*O*invd + xin (fp32).  MODE 1: oh (bf16, even attn slots) = O*invd.
template <int MODE>
__global__ void pv_mfma(const unsigned short* __restrict__ vA,
                        const unsigned short* __restrict__ E,
                        const float* __restrict__ invd,
                        const float* __restrict__ xin,
                        const float* __restrict__ gamma,
                        float* __restrict__ outp,
                        unsigned short* __restrict__ ohb) {
  __shared__ unsigned short Al[128][44];   // pad 44: conflict-free b64 frag reads
  __shared__ unsigned short Bl[128][44];
  int blk = blockIdx.x;            // b*128 + s
  int s = blk & 127, b = blk >> 7;
  int t = threadIdx.x;
  int wv = t >> 6, l = t & 63;
  int wc = (wv >> 1) * 64, wx = (wv & 1) * 64;
  const unsigned short* vs = vA + (size_t)(b * 128 + s) * 16384;
  const unsigned short* es = E + (size_t)(b * 128 + s) * 16384;
  f32x4 acc[4][4];
#pragma unroll
  for (int mi = 0; mi < 4; ++mi)
#pragma unroll
    for (int ni = 0; ni < 4; ++ni) acc[mi][ni] = (f32x4){0.f, 0.f, 0.f, 0.f};
  int lrow = t >> 2, lq = t & 3;
  int lm = l & 15, lk = (l >> 4) * 4;
  for (int y0 = 0; y0 < 128; y0 += 32) {
#pragma unroll
    for (int r = 0; r < 2; ++r) {
      int rr = lrow + r * 64;
      uint4 av = *(const uint4*)(vs + (size_t)rr * 128 + y0 + lq * 8);
      uint4 bv = *(const uint4*)(es + (size_t)rr * 128 + y0 + lq * 8);
      *(uint2*)&Al[rr][lq * 8]     = make_uint2(av.x, av.y);
      *(uint2*)&Al[rr][lq * 8 + 4] = make_uint2(av.z, av.w);
      *(uint2*)&Bl[rr][lq * 8]     = make_uint2(bv.x, bv.y);
      *(uint2*)&Bl[rr][lq * 8 + 4] = make_uint2(bv.z, bv.w);
    }
    __syncthreads();
    short8v af[4], bf[4];
#pragma unroll
    for (int mi = 0; mi < 4; ++mi) {
      const unsigned short* ap = &Al[wc + mi * 16 + lm][lk];
      union { uint2 p[2]; short8v v; } u;
      u.p[0] = *(const uint2*)ap;
      u.p[1] = *(const uint2*)(ap + 16);
      af[mi] = u.v;
    }
#pragma unroll
    for (int ni = 0; ni < 4; ++ni) {
      const unsigned short* bp = &Bl[wx + ni * 16 + lm][lk];
      union { uint2 p[2]; short8v v; } u;
      u.p[0] = *(const uint2*)bp;
      u.p[1] = *(const uint2*)(bp + 16);
      bf[ni] = u.v;
    }
#pragma unroll
    for (int mi = 0; mi < 4; ++mi)
#pragma unroll
      for (int ni = 0; ni < 4; ++ni)
        acc[mi][ni] = __builtin_amdgcn_mfma_f32_16x16x32_bf16(af[mi], bf[ni], acc[mi][ni], 0, 0, 0);
    __syncthreads();
  }
  float g = gamma[0];
  int lr4 = (l >> 4) * 4;
#pragma unroll
  for (int ni = 0; ni < 4; ++ni) {
    int xx = wx + ni * 16 + lm;
    float idv = invd[(size_t)(b * 128 + s) * 128 + xx];
#pragma unroll
    for (int mi = 0; mi < 4; ++mi) {
#pragma unroll
      for (int r = 0; r < 4; ++r) {
        int c = wc + mi * 16 + lr4 + r;
        if (MODE == 0) {
          size_t a = (((size_t)(b * 128 + c)) * 128 + s) * 128 + xx;
          outp[a] = g * acc[mi][ni][r] * idv + xin[a];
        } else {
          ohb[(size_t)b * 8388608ULL + (size_t)s * 16384 + (size_t)c * 128 + xx] =
              f2bf(acc[mi][ni][r] * idv);
        }
      }
    }
  }
}

// K7: out[b][c][x][w] += gamma * oh[b][w][c][x]  (oh bf16 in even attn slots)
__global__ void merge_k(const float* __restrict__ retb, const float* __restrict__ gamma,
                        float* __restrict__ outp) {
  __shared__ float tile[64][65];
  const unsigned short* ohp = (const unsigned short*)retb;
  int blk = blockIdx.x;
  int q = blk & 3, c = (blk >> 2) & 127, b = blk >> 9;
  int x0 = (q >> 1) * 64, w0 = (q & 1) * 64;
  int t = threadIdx.x, lane = t & 63, r0 = (t >> 6) * 16;
  for (int r = r0; r < r0 + 16; ++r)
    tile[r][lane] =
        bf2f(ohp[(size_t)b * 8388608ULL + (size_t)(w0 + r) * 16384 + c * 128 + x0 + lane]);
  __syncthreads();
  float g = gamma[0];
  for (int r = r0; r < r0 + 16; ++r) {
    size_t a = (((size_t)(b * 128 + c)) * 128 + x0 + r) * 128 + w0 + lane;
    outp[a] += g * tile[lane][r];
  }
}

// K8: attn writer (bf16 src). Block (b,i): ret[b][slot][y][i][j] = src*invd_ij.
// HM=1: src=E_h plane (b,j) row i -> even slot (attn_h). HM=0: src=E_w plane (b,i) -> odd.
template <int HM>
__global__ void ret_write(const unsigned short* __restrict__ src, const float* __restrict__ invd,
                          float* __restrict__ retb) {
  __shared__ float tile[128][129];
  __shared__ float idv[128];
  int slab = blockIdx.x;            // b*128 + i
  int b = slab >> 7, i = slab & 127;
  int t = threadIdx.x;
#pragma unroll
  for (int r = 0; r < 8; ++r) {
    int idx = r * 2048 + t * 8;
    int j = idx >> 7, y = idx & 127;
    uint4 raw;
    if (HM == 0)
      raw = *(const uint4*)(src + (size_t)slab * 16384 + j * 128 + y);
    else
      raw = *(const uint4*)(src + (size_t)(b * 128 + j) * 16384 + i * 128 + y);
    unsigned int wd[4] = {raw.x, raw.y, raw.z, raw.w};
#pragma unroll
    for (int e = 0; e < 4; ++e) {
      tile[j][y + 2 * e]     = __uint_as_float((wd[e] & 0xFFFFu) << 16);
      tile[j][y + 2 * e + 1] = __uint_as_float(wd[e] & 0xFFFF0000u);
    }
  }
  if (t < 128) idv[t] = invd[(size_t)slab * 128 + t];
  __syncthreads();
  float* dp = retb + (size_t)b * BSTR_ + (HM == 0 ? SLOT_ : 0);
#pragma unroll
  for (int r = 0; r < 16; ++r) {
    int idx = r * 1024 + t * 4;
    int y = idx >> 7, j = idx & 127;
    float4 o;
    o.x = tile[j][y]     * idv[j];
    o.y = tile[j + 1][y] * idv[j + 1];
    o.z = tile[j + 2][y] * idv[j + 2];
    o.w = tile[j + 3][y] * idv[j + 3];
    *(float4*)&dp[(size_t)y * 16384 + i * 128 + j] = o;
  }
}

extern "C" void kernel_launch(void* const* d_in, const int* in_sizes, int n_in,
                              void* d_out, int out_size, void* d_ws, size_t ws_size,
                              hipStream_t stream) {
  const float* x     = (const float*)d_in[0];
  const float* Wq    = (const float*)d_in[1];
  const float* bq    = (const float*)d_in[2];
  const float* Wk    = (const float*)d_in[3];
  const float* bk    = (const float*)d_in[4];
  const float* Wv    = (const float*)d_in[5];
  const float* bv    = (const float*)d_in[6];
  const float* gamma = (const float*)d_in[7];

  float* outp = (float*)d_out;                 // final out (8M floats)
  float* retb = outp + (size_t)8388608;        // attn region [b][2][y][i][j]
  unsigned short* ohb = (unsigned short*)retb; // bf16 oh in even slots (pre-ret_write)

  // ws bytes: [0,16.78M) q,k,qT,kT fp32 -> then vA0 bf16 (exact overlay, after scores)
  //           [16.78,33.55M) vA1 bf16 ; [33.55,50.33M) E_w bf16 ; [50.33,67.11M) E_h bf16
  //           [67.11M, 68.16M) rsum_w/rsum_h/invd_ij/invd_ji fp32  (== proven budget)
  float* ws      = (float*)d_ws;
  float* q_hwc   = ws;
  float* k_hwc   = ws + (size_t)1048576;
  float* qT      = ws + (size_t)2097152;
  float* kT      = ws + (size_t)3145728;
  unsigned short* vA0 = (unsigned short*)ws;
  unsigned short* vA1 = (unsigned short*)(ws + (size_t)4194304);
  unsigned short* E_w = (unsigned short*)(ws + (size_t)8388608);
  unsigned short* E_h = (unsigned short*)(ws + (size_t)12582912);
  float* rsum_w  = ws + (size_t)16777216;
  float* rsum_h  = ws + (size_t)16842752;
  float* invd_ij = ws + (size_t)16908288;
  float* invd_ji = ws + (size_t)16973824;

  qk_proj<<<1024, 256, 0, stream>>>(x, Wq, bq, Wk, bk, q_hwc, k_hwc, qT, kT);
  score_b<0><<<512, 256, 0, stream>>>(q_hwc, k_hwc, E_w, rsum_w);
  score_b<1><<<512, 256, 0, stream>>>(qT, kT, E_h, rsum_h);
  invd_k<<<256, 256, 0, stream>>>(rsum_w, rsum_h, invd_ij, invd_ji);
  v_proj_bf<<<512, 256, 0, stream>>>(x, Wv, bv, vA0);          // q/k/qT/kT now dead
  trans_v<<<2048, 256, 0, stream>>>(vA0, vA1);
  pv_mfma<0><<<512, 256, 0, stream>>>(vA0, E_w, invd_ij, x, gamma, outp, ohb);
  pv_mfma<1><<<512, 256, 0, stream>>>(vA1, E_h, invd_ji, x, gamma, outp, ohb);
  merge_k<<<2048, 256, 0, stream>>>(retb, gamma, outp);
  ret_write<1><<<512, 256, 0, stream>>>(E_h, invd_ij, retb);   // even slots (attn_h)
  ret_write<0><<<512, 256, 0, stream>>>(E_w, invd_ij, retb);   // odd slots (attn_w)
}

// Round 10
// 152.658 us; speedup vs baseline: 1.5617x; 1.0696x over previous
//
#include <hip/hip_runtime.h>
#include <math.h>

#define HW_ 16384
#define SLOT_ 2097152ULL     // 128^3 floats (one attn plane)
#define BSTR_ 4194304ULL     // per-batch float stride in attn region (2 slots)

typedef __attribute__((ext_vector_type(8))) short short8v;   // 8 bf16 = 4 VGPR
typedef __attribute__((ext_vector_type(4))) float f32x4;

__device__ __forceinline__ unsigned short f2bf(float f) {
  unsigned int u = __float_as_uint(f);
  u = (u + 0x7FFFu + ((u >> 16) & 1u)) >> 16;   // RNE
  return (unsigned short)u;
}
__device__ __forceinline__ float bf2f(unsigned short h) {
  return __uint_as_float(((unsigned int)h) << 16);
}

// K1: fused q,k,v projection. Block = (b,h): 128 pixels. Reads x ONCE.
// v: 8x8 reg tile per thread (tc=ch-group, tx=px-group) -> bf16 vA0[b][h][c][w].
// qk: 2 ch x 8 px per thread against the same Xc tile -> fp32 q/k pixel-major.
__global__ void qkv_proj(const float* __restrict__ x,
                         const float* __restrict__ Wq, const float* __restrict__ bq,
                         const float* __restrict__ Wk, const float* __restrict__ bk,
                         const float* __restrict__ Wv, const float* __restrict__ bv,
                         float* __restrict__ qo, float* __restrict__ ko,
                         unsigned short* __restrict__ vA0) {
  __shared__ float WT[128][36];      // qk weights [c][och] (och<16: q, >=16: k)
  __shared__ float BUF[8448];        // Wc[32][132] | Xc[32][132]; epilogue: QKs[128][36]
  float (*Wc)[132] = (float(*)[132])BUF;
  float (*Xc)[132] = (float(*)[132])(BUF + 4224);
  int t = threadIdx.x;
  for (int i = t; i < 4096; i += 256) {
    int o = i >> 7, c = i & 127;
    WT[c][o] = (o < 16) ? Wq[o * 128 + c] : Wk[(o - 16) * 128 + c];
  }
  int blk = blockIdx.x;              // b*128 + h
  int b = blk >> 7, h = blk & 127;
  int p0 = h * 128;
  int tc = t & 15, tx = t >> 4;
  float acc[8][8];
#pragma unroll
  for (int ci = 0; ci < 8; ++ci) {
    float bvv = bv[tc * 8 + ci];
#pragma unroll
    for (int pi = 0; pi < 8; ++pi) acc[ci][pi] = bvv;
  }
  float accqk[2][8];
#pragma unroll
  for (int e = 0; e < 2; ++e) {
    int och = tc * 2 + e;
    float bias = (och < 16) ? bq[och] : bk[och - 16];
#pragma unroll
    for (int pi = 0; pi < 8; ++pi) accqk[e][pi] = bias;
  }
  int c2 = t >> 1, part = t & 1;
  __syncthreads();   // WT ready
  for (int k0 = 0; k0 < 128; k0 += 32) {
#pragma unroll
    for (int qq = 0; qq < 4; ++qq) {
      int y4 = part * 16 + qq * 4;
      float4 w4 = *(const float4*)&Wv[c2 * 128 + k0 + y4];
      Wc[y4 + 0][c2] = w4.x;
      Wc[y4 + 1][c2] = w4.y;
      Wc[y4 + 2][c2] = w4.z;
      Wc[y4 + 3][c2] = w4.w;
    }
#pragma unroll
    for (int r = 0; r < 4; ++r) {
      int idx = r * 1024 + t * 4;
      int kl = idx >> 7, ccc = idx & 127;
      *(float4*)&Xc[kl][ccc] =
          *(const float4*)&x[(size_t)b * 128 * HW_ + (size_t)(k0 + kl) * HW_ + p0 + ccc];
    }
    __syncthreads();
    for (int kl = 0; kl < 32; ++kl) {
      float wa[8], xa[8];
      *(float4*)(wa)     = *(const float4*)&Wc[kl][tc * 8];
      *(float4*)(wa + 4) = *(const float4*)&Wc[kl][tc * 8 + 4];
      *(float4*)(xa)     = *(const float4*)&Xc[kl][tx * 8];
      *(float4*)(xa + 4) = *(const float4*)&Xc[kl][tx * 8 + 4];
      float wq0 = WT[k0 + kl][tc * 2];
      float wq1 = WT[k0 + kl][tc * 2 + 1];
#pragma unroll
      for (int ci = 0; ci < 8; ++ci)
#pragma unroll
        for (int pi = 0; pi < 8; ++pi)
          acc[ci][pi] = fmaf(wa[ci], xa[pi], acc[ci][pi]);
#pragma unroll
      for (int pi = 0; pi < 8; ++pi) {
        accqk[0][pi] = fmaf(wq0, xa[pi], accqk[0][pi]);
        accqk[1][pi] = fmaf(wq1, xa[pi], accqk[1][pi]);
      }
    }
    __syncthreads();
  }
  // v epilogue: bf16 [c][w] rows
#pragma unroll
  for (int ci = 0; ci < 8; ++ci) {
    union { unsigned short us[8]; uint4 v; } pk;
#pragma unroll
    for (int pi = 0; pi < 8; ++pi) pk.us[pi] = f2bf(acc[ci][pi]);
    *(uint4*)&vA0[(size_t)(b * 128 + h) * 16384 + (size_t)(tc * 8 + ci) * 128 + tx * 8] = pk.v;
  }
  // qk epilogue: restage via LDS, coalesced pixel-major writes
  float (*QKs)[36] = (float(*)[36])BUF;
#pragma unroll
  for (int e = 0; e < 2; ++e)
#pragma unroll
    for (int pi = 0; pi < 8; ++pi)
      QKs[tx * 8 + pi][tc * 2 + e] = accqk[e][pi];
  __syncthreads();
  int px = t >> 1, sel = t & 1;
  const float* qr = &QKs[px][sel * 16];
  float* dst = (sel ? ko : qo) + ((size_t)(b * HW_ + h * 128 + px)) * 16;
#pragma unroll
  for (int r = 0; r < 4; ++r) *(float4*)(dst + r * 4) = *(const float4*)(qr + r * 4);
}

// K2: score GEMM + exp + row-sums; E stored bf16 at E + b*ebs + eoff + s*16384
// (shorts). Q/K rows gathered: qb = Q + b*262144 + s*qss; row r at qb + r*qrs.
template <int MASK>
__global__ void score_b(const float* __restrict__ Q, const float* __restrict__ K,
                        unsigned short* __restrict__ E, float* __restrict__ rsum,
                        size_t qss, size_t qrs, size_t ebs, size_t eoff) {
  __shared__ float Qs[16][132];
  __shared__ float Ks[16][132];
  int slab = blockIdx.x;
  int b = slab >> 7, s = slab & 127;
  const float* qb = Q + (size_t)b * 262144 + (size_t)s * qss;
  const float* kb = K + (size_t)b * 262144 + (size_t)s * qss;
  int t = threadIdx.x;
  int cc = t & 15;
  int pb = (t >> 4) * 8;
#pragma unroll
  for (int u = 0; u < 8; ++u) {
    Qs[cc][pb + u] = qb[(size_t)(pb + u) * qrs + cc];
    Ks[cc][pb + u] = kb[(size_t)(pb + u) * qrs + cc];
  }
  __syncthreads();
  int tr = (t >> 4) * 8;
  int ty = (t & 15) * 8;
  float acc[8][8] = {{0.f}};
#pragma unroll
  for (int c = 0; c < 16; ++c) {
    float qa[8], ka[8];
    *(float4*)(qa)     = *(const float4*)&Qs[c][tr];
    *(float4*)(qa + 4) = *(const float4*)&Qs[c][tr + 4];
    *(float4*)(ka)     = *(const float4*)&Ks[c][ty];
    *(float4*)(ka + 4) = *(const float4*)&Ks[c][ty + 4];
#pragma unroll
    for (int u = 0; u < 8; ++u)
#pragma unroll
      for (int v = 0; v < 8; ++v)
        acc[u][v] = fmaf(qa[u], ka[v], acc[u][v]);
  }
  float rp[8];
#pragma unroll
  for (int u = 0; u < 8; ++u) {
    rp[u] = 0.f;
#pragma unroll
    for (int v = 0; v < 8; ++v) {
      float e = __expf(acc[u][v]);
      if (MASK && (tr + u) == (ty + v)) e = 0.f;
      acc[u][v] = e;
      rp[u] += e;
    }
  }
  unsigned short* out = E + (size_t)b * ebs + eoff + (size_t)s * 16384;
#pragma unroll
  for (int u = 0; u < 8; ++u) {
    union { unsigned short us[8]; uint4 v; } pk;
#pragma unroll
    for (int v = 0; v < 8; ++v) pk.us[v] = f2bf(acc[u][v]);
    *(uint4*)&out[(tr + u) * 128 + ty] = pk.v;
  }
#pragma unroll
  for (int u = 0; u < 8; ++u) {
    rp[u] += __shfl_xor(rp[u], 1);
    rp[u] += __shfl_xor(rp[u], 2);
    rp[u] += __shfl_xor(rp[u], 4);
    rp[u] += __shfl_xor(rp[u], 8);
  }
  if ((t & 15) == 0) {
#pragma unroll
    for (int u = 0; u < 8; ++u) rsum[(size_t)slab * 128 + tr + u] = rp[u];
  }
}

// K3: per-pixel inverse denominator, (i,j) and (j,i) layouts.
__global__ void invd_k(const float* __restrict__ rsw, const float* __restrict__ rsh,
                       float* __restrict__ dij, float* __restrict__ dji) {
  int p = blockIdx.x * 256 + threadIdx.x;
  int b = p >> 14, rem = p & 16383, i = rem >> 7, j = rem & 127;
  float d = rsw[p] + rsh[(size_t)b * HW_ + j * 128 + i];
  float r = 1.0f / d;
  dij[p] = r;
  dji[(size_t)b * HW_ + j * 128 + i] = r;
}

// K4b: vA1[b][w][c][h] = vA0[b][h][c][w]  (bf16 64x64 tiled transpose per (b,c))
__global__ void trans_v(const unsigned short* __restrict__ vA0, unsigned short* __restrict__ vA1) {
  __shared__ unsigned short tile[64][65];
  int blk = blockIdx.x;            // b(4)*c(128)*quad(4)
  int q = blk & 3, c = (blk >> 2) & 127, b = blk >> 9;
  int h0 = (q >> 1) * 64, w0 = (q & 1) * 64;
  int t = threadIdx.x, lane = t & 63, r0 = (t >> 6) * 16;
  for (int r = r0; r < r0 + 16; ++r)
    tile[r][lane] = vA0[(size_t)(b * 128 + h0 + r) * 16384 + c * 128 + w0 + lane];
  __syncthreads();
  for (int r = r0; r < r0 + 16; ++r)
    vA1[(size_t)(b * 128 + w0 + r) * 16384 + c * 128 + h0 + lane] = tile[lane][r];
}

// K5/K6: PV via MFMA. O[c][x] = sum_y A[c][y]*B[y][x], A = vA slab, B^T = E slab
// (E plane at E + b*ebs + eoff + s*16384 shorts). 4 waves, each 64x64 output.
// MODE 0: out = g*O*invd + xin (fp32).  MODE 1: oh (bf16, even attn slots) = O*invd.
template <int MODE>
__global__ void pv_mfma(const unsigned short* __restrict__ vA,
                        const unsigned short* __restrict__ E,
                        const float* __restrict__ invd,
                        const float* __restrict__ xin,
                        const float* __restrict__ gamma,
                        float* __restrict__ outp,
                        unsigned short* __restrict__ ohb,
                        size_t ebs, size_t eoff) {
  __shared__ unsigned short Al[128][44];
  __shared__ unsigned short Bl[128][44];
  int blk = blockIdx.x;            // b*128 + s
  int s = blk & 127, b = blk >> 7;
  int t = threadIdx.x;
  int wv = t >> 6, l = t & 63;
  int wc = (wv >> 1) * 64, wx = (wv & 1) * 64;
  const unsigned short* vs = vA + (size_t)(b * 128 + s) * 16384;
  const unsigned short* es = E + (size_t)b * ebs + eoff + (size_t)s * 16384;
  f32x4 acc[4][4];
#pragma unroll
  for (int mi = 0; mi < 4; ++mi)
#pragma unroll
    for (int ni = 0; ni < 4; ++ni) acc[mi][ni] = (f32x4){0.f, 0.f, 0.f, 0.f};
  int lrow = t >> 2, lq = t & 3;
  int lm = l & 15, lk = (l >> 4) * 4;
  for (int y0 = 0; y0 < 128; y0 += 32) {
#pragma unroll
    for (int r = 0; r < 2; ++r) {
      int rr = lrow + r * 64;
      uint4 av = *(const uint4*)(vs + (size_t)rr * 128 + y0 + lq * 8);
      uint4 bv = *(const uint4*)(es + (size_t)rr * 128 + y0 + lq * 8);
      *(uint2*)&Al[rr][lq * 8]     = make_uint2(av.x, av.y);
      *(uint2*)&Al[rr][lq * 8 + 4] = make_uint2(av.z, av.w);
      *(uint2*)&Bl[rr][lq * 8]     = make_uint2(bv.x, bv.y);
      *(uint2*)&Bl[rr][lq * 8 + 4] = make_uint2(bv.z, bv.w);
    }
    __syncthreads();
    short8v af[4], bf[4];
#pragma unroll
    for (int mi = 0; mi < 4; ++mi) {
      const unsigned short* ap = &Al[wc + mi * 16 + lm][lk];
      union { uint2 p[2]; short8v v; } u;
      u.p[0] = *(const uint2*)ap;
      u.p[1] = *(const uint2*)(ap + 16);
      af[mi] = u.v;
    }
#pragma unroll
    for (int ni = 0; ni < 4; ++ni) {
      const unsigned short* bp = &Bl[wx + ni * 16 + lm][lk];
      union { uint2 p[2]; short8v v; } u;
      u.p[0] = *(const uint2*)bp;
      u.p[1] = *(const uint2*)(bp + 16);
      bf[ni] = u.v;
    }
#pragma unroll
    for (int mi = 0; mi < 4; ++mi)
#pragma unroll
      for (int ni = 0; ni < 4; ++ni)
        acc[mi][ni] = __builtin_amdgcn_mfma_f32_16x16x32_bf16(af[mi], bf[ni], acc[mi][ni], 0, 0, 0);
    __syncthreads();
  }
  float g = gamma[0];
  int lr4 = (l >> 4) * 4;
#pragma unroll
  for (int ni = 0; ni < 4; ++ni) {
    int xx = wx + ni * 16 + lm;
    float idv = invd[(size_t)(b * 128 + s) * 128 + xx];
#pragma unroll
    for (int mi = 0; mi < 4; ++mi) {
#pragma unroll
      for (int r = 0; r < 4; ++r) {
        int c = wc + mi * 16 + lr4 + r;
        if (MODE == 0) {
          size_t a = (((size_t)(b * 128 + c)) * 128 + s) * 128 + xx;
          outp[a] = g * acc[mi][ni][r] * idv + xin[a];
        } else {
          ohb[(size_t)b * 8388608ULL + (size_t)s * 16384 + (size_t)c * 128 + xx] =
              f2bf(acc[mi][ni][r] * idv);
        }
      }
    }
  }
}

// K7: out[b][c][x][w] += gamma * oh[b][w][c][x]  (oh bf16 in even attn slots)
__global__ void merge_k(const float* __restrict__ retb, const float* __restrict__ gamma,
                        float* __restrict__ outp) {
  __shared__ float tile[64][65];
  const unsigned short* ohp = (const unsigned short*)retb;
  int blk = blockIdx.x;
  int q = blk & 3, c = (blk >> 2) & 127, b = blk >> 9;
  int x0 = (q >> 1) * 64, w0 = (q & 1) * 64;
  int t = threadIdx.x, lane = t & 63, r0 = (t >> 6) * 16;
  for (int r = r0; r < r0 + 16; ++r)
    tile[r][lane] =
        bf2f(ohp[(size_t)b * 8388608ULL + (size_t)(w0 + r) * 16384 + c * 128 + x0 + lane]);
  __syncthreads();
  float g = gamma[0];
  for (int r = r0; r < r0 + 16; ++r) {
    size_t a = (((size_t)(b * 128 + c)) * 128 + x0 + r) * 128 + w0 + lane;
    outp[a] += g * tile[lane][r];
  }
}

// K8: attn writer (bf16 src at src + b*sbs + soff + plane*16384).
// HM=0: plane=i (slab), rows j -> odd slot (attn_w). HM=1: plane=j, row i -> even (attn_h).
template <int HM>
__global__ void ret_write(const unsigned short* __restrict__ src, const float* __restrict__ invd,
                          float* __restrict__ retb, size_t sbs, size_t soff) {
  __shared__ float tile[128][129];
  __shared__ float idv[128];
  int slab = blockIdx.x;            // b*128 + i
  int b = slab >> 7, i = slab & 127;
  int t = threadIdx.x;
  const unsigned short* sp = src + (size_t)b * sbs + soff;
#pragma unroll
  for (int r = 0; r < 8; ++r) {
    int idx = r * 2048 + t * 8;
    int j = idx >> 7, y = idx & 127;
    uint4 raw;
    if (HM == 0)
      raw = *(const uint4*)(sp + (size_t)i * 16384 + j * 128 + y);
    else
      raw = *(const uint4*)(sp + (size_t)j * 16384 + i * 128 + y);
    unsigned int wd[4] = {raw.x, raw.y, raw.z, raw.w};
#pragma unroll
    for (int e = 0; e < 4; ++e) {
      tile[j][y + 2 * e]     = __uint_as_float((wd[e] & 0xFFFFu) << 16);
      tile[j][y + 2 * e + 1] = __uint_as_float(wd[e] & 0xFFFF0000u);
    }
  }
  if (t < 128) idv[t] = invd[(size_t)slab * 128 + t];
  __syncthreads();
  float* dp = retb + (size_t)b * BSTR_ + (HM == 0 ? SLOT_ : 0);
#pragma unroll
  for (int r = 0; r < 16; ++r) {
    int idx = r * 1024 + t * 4;
    int y = idx >> 7, j = idx & 127;
    float4 o;
    o.x = tile[j][y]     * idv[j];
    o.y = tile[j + 1][y] * idv[j + 1];
    o.z = tile[j + 2][y] * idv[j + 2];
    o.w = tile[j + 3][y] * idv[j + 3];
    *(float4*)&dp[(size_t)y * 16384 + i * 128 + j] = o;
  }
}

extern "C" void kernel_launch(void* const* d_in, const int* in_sizes, int n_in,
                              void* d_out, int out_size, void* d_ws, size_t ws_size,
                              hipStream_t stream) {
  const float* x     = (const float*)d_in[0];
  const float* Wq    = (const float*)d_in[1];
  const float* bq    = (const float*)d_in[2];
  const float* Wk    = (const float*)d_in[3];
  const float* bk    = (const float*)d_in[4];
  const float* Wv    = (const float*)d_in[5];
  const float* bv    = (const float*)d_in[6];
  const float* gamma = (const float*)d_in[7];

  float* outp = (float*)d_out;                 // final out (8M floats)
  float* retb = outp + (size_t)8388608;        // attn region [b][2][y][i][j]
  unsigned short* ohb = (unsigned short*)retb; // bf16 oh in even slots (pre-ret_write)
  unsigned short* ehb = (unsigned short*)retb; // bf16 E_h in odd slots: + b*8388608 + 4194304

  // ws floats: q[0,1M) k[1M,2M) vA0 bf16 [2M,6M) vA1 bf16 [6M,10M) E_w bf16 [10M,14M)
  //            rsum_w/rsum_h/invd_ij/invd_ji [14680064..+4*65536) ; total 59.8 MB
  float* ws      = (float*)d_ws;
  float* q_hwc   = ws;
  float* k_hwc   = ws + (size_t)1048576;
  unsigned short* vA0 = (unsigned short*)(ws + (size_t)2097152);
  unsigned short* vA1 = (unsigned short*)(ws + (size_t)6291456);
  unsigned short* E_w = (unsigned short*)(ws + (size_t)10485760);
  float* rsum_w  = ws + (size_t)14680064;
  float* rsum_h  = ws + (size_t)14745600;
  float* invd_ij = ws + (size_t)14811136;
  float* invd_ji = ws + (size_t)14876672;

  qkv_proj<<<512, 256, 0, stream>>>(x, Wq, bq, Wk, bk, Wv, bv, q_hwc, k_hwc, vA0);
  score_b<0><<<512, 256, 0, stream>>>(q_hwc, k_hwc, E_w, rsum_w,
                                      (size_t)2048, (size_t)16, (size_t)2097152, (size_t)0);
  score_b<1><<<512, 256, 0, stream>>>(q_hwc, k_hwc, ehb, rsum_h,
                                      (size_t)16, (size_t)2048, (size_t)8388608, (size_t)4194304);
  invd_k<<<256, 256, 0, stream>>>(rsum_w, rsum_h, invd_ij, invd_ji);
  trans_v<<<2048, 256, 0, stream>>>(vA0, vA1);
  pv_mfma<0><<<512, 256, 0, stream>>>(vA0, E_w, invd_ij, x, gamma, outp, ohb,
                                      (size_t)2097152, (size_t)0);
  pv_mfma<1><<<512, 256, 0, stream>>>(vA1, ehb, invd_ji, x, gamma, outp, ohb,
                                      (size_t)8388608, (size_t)4194304);
  merge_k<<<2048, 256, 0, stream>>>(retb, gamma, outp);
  ret_write<1><<<512, 256, 0, stream>>>(ehb, invd_ij, retb, (size_t)8388608, (size_t)4194304);
  ret_write<0><<<512, 256, 0, stream>>>(E_w, invd_ij, retb, (size_t)2097152, (size_t)0);
}